// Round 9
// baseline (158.156 us; speedup 1.0000x reference)
//
#include <hip/hip_runtime.h>
#include <hip/hip_bf16.h>
#include <cmath>

#define H_ 128
#define W_ 128
#define HW_ 16384
#define C_ 64
#define N_ 8
#define BN_EPS 1e-5f

typedef __attribute__((ext_vector_type(8))) short short8;
typedef __attribute__((ext_vector_type(4))) float float4_;
typedef __attribute__((ext_vector_type(4))) unsigned uint4_;
typedef __attribute__((ext_vector_type(2))) unsigned uint2_;

__device__ inline short f2bf(float f) {
    unsigned u = __builtin_bit_cast(unsigned, f);
    u += 0x7fffu + ((u >> 16) & 1u);     // RNE
    return (short)(u >> 16);
}
__device__ inline float bf2f(short s) {
    unsigned u = ((unsigned)(unsigned short)s) << 16;
    return __builtin_bit_cast(float, u);
}
// packed RNE fp32x2 -> bf16x2 (v_cvt_pk_bf16_f32 on gfx950)
__device__ inline unsigned pkbf2(float a, float b) {
    __hip_bfloat162 h = __float22bfloat162_rn(make_float2(a, b));
    unsigned u;
    __builtin_memcpy(&u, &h, 4);
    return u;
}
__device__ inline float bperm_f(int addr, float v) {
    return __builtin_bit_cast(float,
        __builtin_amdgcn_ds_bpermute(addr, __builtin_bit_cast(int, v)));
}
__device__ inline float bfu_lo(unsigned u) {      // low bf16 of dword -> f32
    return __builtin_bit_cast(float, u << 16);
}
__device__ inline float bfu_hi(unsigned u) {      // high bf16 of dword -> f32
    return __builtin_bit_cast(float, u & 0xffff0000u);
}

#if __has_builtin(__builtin_amdgcn_fdot2_f32_bf16)
#define HAS_FDOT2 1
typedef __bf16 bf16x2v __attribute__((ext_vector_type(2)));
__device__ inline float fdot2bf(unsigned a, unsigned b, float c) {
    return __builtin_amdgcn_fdot2_f32_bf16(
        __builtin_bit_cast(bf16x2v, a), __builtin_bit_cast(bf16x2v, b), c, false);
}
#else
#define HAS_FDOT2 0
#endif

// ---- workspace layout (bytes) ----
#define XR8_OFS    0
#define WDEFB_OFS  16777216
#define BT27_OFS   16850944
#define BT9_OFS    16888320

#define PS_ 402   // patch plane stride (short8): c8-plane offset 1608 dw, %32=8

// ---------------- weight prep ----------------
__global__ __launch_bounds__(256) void prep_w(
    const float* __restrict__ w_off, const float* __restrict__ w_def,
    const float* __restrict__ w1, short* __restrict__ wdefB,
    short* __restrict__ bt27, short* __restrict__ bt9)
{
    int i = blockIdx.x * 256 + threadIdx.x;
    if (i < 36864) {
        int o = i / 576, r = i - o*576, t = r >> 6, c = r & 63;
        wdefB[i] = f2bf(w_def[o*576 + c*9 + t]);
    } else if (i < 36864 + 18688) {
        int j = i - 36864;
        int oc = j / 584, K = j - oc*584;
        float v = 0.f;
        if (oc < 27 && K < 576) { int t = K >> 6, c = K & 63; v = w_off[oc*576 + c*9 + t]; }
        bt27[j] = f2bf(v);
    } else if (i < 36864 + 18688 + 9344) {
        int j = i - 36864 - 18688;
        int oc = j / 584, K = j - oc*584;
        float v = 0.f;
        if (oc < 9 && K < 576) { int t = K >> 6, c = K & 63; v = w1[oc*576 + c*9 + t]; }
        bt9[j] = f2bf(v);
    }
}

// ======= fused: convert + conv27(offsets,filt) + deformable conv + residual ====
// 16x16 px tile, 256 thr (4 waves), one barrier. conv27 AND deform both use
// swapped operands (A=weights, B=samples) so D = [oc][pixel]: offsets hand off
// via ds_bpermute, and the epilogue stores 4 consecutive channels per lane
// (ds_read_b64 residual + dwordx2 global store).
__global__ __launch_bounds__(256, 2) void fused_off_deform(
    const float* __restrict__ x, const short8* __restrict__ btg27,
    const short8* __restrict__ wdefB, float* __restrict__ filt_out,
    short* __restrict__ xr8s)
{
    __shared__ short8 patch[8*PS_];     // [c8][py*20+px], 51,456 B
    const int tid = threadIdx.x;
    const int bx = blockIdx.x, by = blockIdx.y, n = blockIdx.z;
    const int lane = tid & 63, wid = tid >> 6;
    const int q = lane >> 4, col = lane & 15;
    const int r0 = by*16 - 2, c0 = bx*16 - 2;
    const float* xb = x + (size_t)n * C_ * HW_;

    // ---- stage 20x20 halo patch, fp32 -> bf16 (packed cvt), NC8HW8 in LDS ----
    for (int i = tid; i < 3200; i += 256) {
        int c8 = i / 400, r = i - c8*400;
        int py = r / 20, px = r - py*20;
        int gy = r0 + py, gx = c0 + px;
        uint4_ u = (uint4_){0u,0u,0u,0u};
        if ((unsigned)gy < 128u && (unsigned)gx < 128u) {
            const float* xp = xb + (size_t)(c8*8)*HW_ + gy*W_ + gx;
            u[0] = pkbf2(xp[0],      xp[HW_]);
            u[1] = pkbf2(xp[2*HW_],  xp[3*HW_]);
            u[2] = pkbf2(xp[4*HW_],  xp[5*HW_]);
            u[3] = pkbf2(xp[6*HW_],  xp[7*HW_]);
        }
        patch[c8*PS_ + py*20 + px] = __builtin_bit_cast(short8, u);
    }
    __syncthreads();

    // ---- conv27 phase (A=weights, B=patch) -> D[oc][pixel_col] ----
    float4_ a27[2][4];      // [oc-tile][row i]
    #pragma unroll
    for (int m = 0; m < 2; m++)
        #pragma unroll
        for (int i = 0; i < 4; i++) a27[m][i] = (float4_){0.f,0.f,0.f,0.f};

    #pragma unroll 2
    for (int k0 = 0; k0 < 18; k0++) {
        int t = k0 >> 1;
        int dy = t/3, dx = t - dy*3;
        int c8 = (k0 & 1)*4 + q;
        short8 w0 = btg27[col*73 + k0*4 + q];
        short8 w1 = btg27[(16 + col)*73 + k0*4 + q];
        #pragma unroll
        for (int i = 0; i < 4; i++) {
            int mt = wid*4 + i;
            short8 p = patch[c8*PS_ + (mt + dy + 1)*20 + (col + dx + 1)];
            a27[0][i] = __builtin_amdgcn_mfma_f32_16x16x32_bf16(w0, p, a27[0][i], 0,0,0);
            a27[1][i] = __builtin_amdgcn_mfma_f32_16x16x32_bf16(w1, p, a27[1][i], 0,0,0);
        }
    }

    // filt (oc 18..26) store: oc = 16 + q*4 + reg, pixel (row=wid*4+i, col)
    #pragma unroll
    for (int i = 0; i < 4; i++) {
        int prow = by*16 + wid*4 + i;
        #pragma unroll
        for (int reg = 0; reg < 4; reg++) {
            int oc = 16 + q*4 + reg;
            if (oc >= 18 && oc < 27)
                filt_out[((size_t)n*9 + (oc-18))*HW_ + prow*W_ + bx*16 + col] = a27[1][i][reg];
        }
    }

    // ---- deform phase: per wave 4 rows x 16 pixel_cols, N=64, K=576 ----
    float4_ acc[4][4];
    #pragma unroll
    for (int i = 0; i < 4; i++)
        #pragma unroll
        for (int nt = 0; nt < 4; nt++) acc[i][nt] = (float4_){0.f,0.f,0.f,0.f};

    const int col4 = col*4;
    const int gxc = bx*16 + col;

    // one tap of the deformable conv
    auto tap = [&](int t, int dy, int dx, const float* oy, const float* ox) {
        short8 afrag[4][2];
        #pragma unroll
        for (int i = 0; i < 4; i++) {
            const int gy = by*16 + wid*4 + i;
            float py = (float)(gy + dy) + oy[i];
            float px = (float)(gxc + dx) + ox[i];
            float y0f = floorf(py), x0f = floorf(px);
            float wy1 = py - y0f, wx1 = px - x0f;
            float wy0 = 1.f - wy1, wx0 = 1.f - wx1;
            int y0 = (int)y0f, x0 = (int)x0f;
            int y1 = y0 + 1,   x1 = x0 + 1;
            float wy0v = ((unsigned)y0 < (unsigned)H_) ? wy0 : 0.f;
            float wy1v = ((unsigned)y1 < (unsigned)H_) ? wy1 : 0.f;
            float wx0v = ((unsigned)x0 < (unsigned)W_) ? wx0 : 0.f;
            float wx1v = ((unsigned)x1 < (unsigned)W_) ? wx1 : 0.f;
            float w00 = wy0v*wx0v, w01 = wy0v*wx1v;
            float w10 = wy1v*wx0v, w11 = wy1v*wx1v;
            int cy0 = min(max(y0, 0), H_-1), cy1 = min(max(y1, 0), H_-1);
            int cx0 = min(max(x0, 0), W_-1), cx1 = min(max(x1, 0), W_-1);
            int ly0 = cy0 - r0, ly1 = cy1 - r0;
            int lx0 = cx0 - c0, lx1 = cx1 - c0;
            bool inp = ((unsigned)ly0 < 20u) & ((unsigned)ly1 < 20u)
                     & ((unsigned)lx0 < 20u) & ((unsigned)lx1 < 20u);
#if HAS_FDOT2
            unsigned w01pk = pkbf2(w00, w01);
            unsigned w23pk = pkbf2(w10, w11);
#endif
            #pragma unroll
            for (int ks = 0; ks < 2; ks++) {
                const int c8 = ks*4 + q;
                uint4_ u;
                if (inp) {
                    const short8* pl = &patch[c8*PS_];
                    short8 p00 = pl[ly0*20 + lx0], p01 = pl[ly0*20 + lx1];
                    short8 p10 = pl[ly1*20 + lx0], p11 = pl[ly1*20 + lx1];
#if HAS_FDOT2
                    uint4_ u00 = __builtin_bit_cast(uint4_, p00);
                    uint4_ u01 = __builtin_bit_cast(uint4_, p01);
                    uint4_ u10 = __builtin_bit_cast(uint4_, p10);
                    uint4_ u11 = __builtin_bit_cast(uint4_, p11);
                    #pragma unroll
                    for (int d = 0; d < 4; d++) {
                        unsigned lo01 = __builtin_amdgcn_perm(u01[d], u00[d], 0x05040100u);
                        unsigned hi01 = __builtin_amdgcn_perm(u01[d], u00[d], 0x07060302u);
                        unsigned lo23 = __builtin_amdgcn_perm(u11[d], u10[d], 0x05040100u);
                        unsigned hi23 = __builtin_amdgcn_perm(u11[d], u10[d], 0x07060302u);
                        float slo = fdot2bf(lo01, w01pk, fdot2bf(lo23, w23pk, 0.f));
                        float shi = fdot2bf(hi01, w01pk, fdot2bf(hi23, w23pk, 0.f));
                        u[d] = pkbf2(slo, shi);
                    }
#else
                    float s[8];
                    #pragma unroll
                    for (int j = 0; j < 8; j++)
                        s[j] = bf2f(p00[j])*w00 + bf2f(p01[j])*w01
                             + bf2f(p10[j])*w10 + bf2f(p11[j])*w11;
                    u[0] = pkbf2(s[0],s[1]); u[1] = pkbf2(s[2],s[3]);
                    u[2] = pkbf2(s[4],s[5]); u[3] = pkbf2(s[6],s[7]);
#endif
                } else {
                    // rare (|off| >= ~1): exact global fp32 fallback
                    const float* xg = xb + (size_t)(c8*8)*HW_;
                    float s[8];
                    #pragma unroll
                    for (int j = 0; j < 8; j++) {
                        const float* xj = xg + (size_t)j*HW_;
                        s[j] = xj[cy0*W_+cx0]*w00 + xj[cy0*W_+cx1]*w01
                             + xj[cy1*W_+cx0]*w10 + xj[cy1*W_+cx1]*w11;
                    }
                    u[0] = pkbf2(s[0],s[1]); u[1] = pkbf2(s[2],s[3]);
                    u[2] = pkbf2(s[4],s[5]); u[3] = pkbf2(s[6],s[7]);
                }
                afrag[i][ks] = __builtin_bit_cast(short8, u);
            }
        }
        // swapped: A=weights, B=samples -> D[oc][pixel]
        #pragma unroll
        for (int ks = 0; ks < 2; ks++) {
            #pragma unroll
            for (int nt = 0; nt < 4; nt++) {
                short8 b = wdefB[(size_t)(nt*16 + col)*72 + t*8 + ks*4 + q];
                #pragma unroll
                for (int i = 0; i < 4; i++)
                    acc[i][nt] = __builtin_amdgcn_mfma_f32_16x16x32_bf16(
                        b, afrag[i][ks], acc[i][nt], 0,0,0);
            }
        }
    };

    // ---- tap t=8 first (offsets oc 16,17 live in a27[1] regs 0,1) ----
    {
        float oy[4], ox[4];
        #pragma unroll
        for (int i = 0; i < 4; i++) {
            oy[i] = bperm_f(col4, a27[1][i][0]);
            ox[i] = bperm_f(col4, a27[1][i][1]);
        }
        tap(8, 1, 1, oy, ox);      // a27[1] dead after this point
    }
    // ---- taps t=0..7 (offsets oc 2t,2t+1 in a27[0]; reg parity by t&1) ----
    #pragma unroll 1
    for (int t = 0; t < 8; t++) {
        const int addr = ((t >> 1) << 6) + col4;   // src lane = (t>>1)*16 + col
        float oy[4], ox[4];
        #pragma unroll
        for (int i = 0; i < 4; i++) {
            float oyA = bperm_f(addr, a27[0][i][0]);
            float oyB = bperm_f(addr, a27[0][i][2]);
            float oxA = bperm_f(addr, a27[0][i][1]);
            float oxB = bperm_f(addr, a27[0][i][3]);
            oy[i] = (t & 1) ? oyB : oyA;
            ox[i] = (t & 1) ? oxB : oxA;
        }
        int dy = t/3 - 1, dx = (t - (t/3)*3) - 1;
        tap(t, dy, dx, oy, ox);
    }

    // ---- epilogue: lane holds 4 consecutive channels of pixel (row i, col) ----
    // oc = nt*16 + q*4 + reg -> c8 = 2nt + (q>>1), inner = (q&1)*4
    const short* ps = (const short*)patch;
    short* xout = xr8s + (size_t)n*8*HW_*8;
    const int inner = (q & 1) * 4;
    #pragma unroll
    for (int i = 0; i < 4; i++) {
        const int row = wid*4 + i;
        const int pix = (by*16 + row)*W_ + bx*16 + col;
        #pragma unroll
        for (int nt = 0; nt < 4; nt++) {
            const int c8 = 2*nt + (q >> 1);
            // residual: 4 consecutive bf16 channels from patch (ds_read_b64)
            const unsigned* pw = (const unsigned*)(ps
                + ((c8*PS_ + (row+2)*20 + (col+2)) << 3) + inner);
            unsigned r0 = pw[0], r1 = pw[1];
            float v0 = acc[i][nt][0] + bfu_lo(r0);
            float v1 = acc[i][nt][1] + bfu_hi(r0);
            float v2 = acc[i][nt][2] + bfu_lo(r1);
            float v3 = acc[i][nt][3] + bfu_hi(r1);
            uint2_ o2 = (uint2_){ pkbf2(v0, v1), pkbf2(v2, v3) };
            *(uint2_*)(xout + (((size_t)c8*HW_ + pix) << 3) + inner) = o2;
        }
    }
}

// ---------------- conv9 + BN + ReLU (B direct from global, L1-hot) -----------
__global__ __launch_bounds__(256) void conv9_mfma(
    const short8* __restrict__ xr8, const short8* __restrict__ btg,
    const float* __restrict__ gamma, const float* __restrict__ beta,
    const float* __restrict__ mean, const float* __restrict__ var,
    float* __restrict__ out)
{
    __shared__ short8 patch[8*325];
    const int tid = threadIdx.x;
    const int bx = blockIdx.x, by = blockIdx.y, n = blockIdx.z;

    for (int i = tid; i < 2592; i += 256) {
        int c8 = i / 324, r = i - c8*324;
        int py = r / 18, px = r - py*18;
        int gy = by*16 - 1 + py, gx = bx*16 - 1 + px;
        short8 v = {0,0,0,0,0,0,0,0};
        if ((unsigned)gy < 128u && (unsigned)gx < 128u)
            v = xr8[(size_t)(n*8 + c8)*HW_ + gy*W_ + gx];
        patch[c8*325 + py*18 + px] = v;
    }
    __syncthreads();

    const int lane = tid & 63, wid = tid >> 6;
    const int q = lane >> 4, col = lane & 15;
    float4_ acc[4];
    #pragma unroll
    for (int i = 0; i < 4; i++) acc[i] = (float4_){0.f,0.f,0.f,0.f};

    #pragma unroll 2
    for (int k0 = 0; k0 < 18; k0++) {
        int t = k0 >> 1;
        int dy = t/3, dx = t - dy*3;
        int c8 = (k0 & 1)*4 + q;
        short8 b0 = btg[col*73 + k0*4 + q];
        #pragma unroll
        for (int i = 0; i < 4; i++) {
            int mt = wid*4 + i;
            short8 a = patch[c8*325 + (mt + dy)*18 + (col + dx)];
            acc[i] = __builtin_amdgcn_mfma_f32_16x16x32_bf16(a, b0, acc[i], 0,0,0);
        }
    }

    float sc = 0.f, sh = 0.f;
    if (col < 9) {
        sc = gamma[col] * rsqrtf(var[col] + BN_EPS);
        sh = beta[col] - mean[col] * sc;
    }
    #pragma unroll
    for (int i = 0; i < 4; i++) {
        int mt = wid*4 + i;
        if (col < 9) {
            int pix0 = (by*16 + mt)*W_ + bx*16 + q*4;
            float4_ v;
            #pragma unroll
            for (int reg = 0; reg < 4; reg++)
                v[reg] = fmaxf(fmaf(acc[i][reg], sc, sh), 0.f);
            *(float4_*)&out[((size_t)n*9 + col)*HW_ + pix0] = v;
        }
    }
}

extern "C" void kernel_launch(void* const* d_in, const int* in_sizes, int n_in,
                              void* d_out, int out_size, void* d_ws, size_t ws_size,
                              hipStream_t stream)
{
    const float* x     = (const float*)d_in[0];
    const float* w_off = (const float*)d_in[1];
    const float* w_def = (const float*)d_in[2];
    const float* w1    = (const float*)d_in[3];
    const float* gamma = (const float*)d_in[4];
    const float* beta  = (const float*)d_in[5];
    const float* mean  = (const float*)d_in[6];
    const float* var   = (const float*)d_in[7];
    float* out = (float*)d_out;

    char* ws = (char*)d_ws;
    short8* xr8     = (short8*)(ws + XR8_OFS);
    short*  wdefB   = (short*)(ws + WDEFB_OFS);
    short*  bt27    = (short*)(ws + BT27_OFS);
    short*  bt9     = (short*)(ws + BT9_OFS);

    float* h_out    = out;
    float* filt_out = out + (size_t)N_ * 9 * HW_;

    prep_w<<<dim3(254), dim3(256), 0, stream>>>(w_off, w_def, w1, wdefB, bt27, bt9);

    dim3 cgrid(8, 8, 8);
    fused_off_deform<<<cgrid, dim3(256), 0, stream>>>(
        x, (const short8*)bt27, (const short8*)wdefB, filt_out, (short*)xr8);
    conv9_mfma<<<cgrid, dim3(256), 0, stream>>>(
        xr8, (const short8*)bt9, gamma, beta, mean, var, h_out);
}

// Round 13
// 157.830 us; speedup vs baseline: 1.0021x; 1.0021x over previous
//
#include <hip/hip_runtime.h>
#include <hip/hip_bf16.h>
#include <cmath>

#define H_ 128
#define W_ 128
#define HW_ 16384
#define C_ 64
#define N_ 8
#define BN_EPS 1e-5f

typedef __attribute__((ext_vector_type(8))) short short8;
typedef __attribute__((ext_vector_type(4))) float float4_;
typedef __attribute__((ext_vector_type(4))) unsigned uint4_;
typedef __attribute__((ext_vector_type(2))) unsigned uint2_;

__device__ inline short f2bf(float f) {
    unsigned u = __builtin_bit_cast(unsigned, f);
    u += 0x7fffu + ((u >> 16) & 1u);     // RNE
    return (short)(u >> 16);
}
__device__ inline float bf2f(short s) {
    unsigned u = ((unsigned)(unsigned short)s) << 16;
    return __builtin_bit_cast(float, u);
}
// packed RNE fp32x2 -> bf16x2 (v_cvt_pk_bf16_f32 on gfx950)
__device__ inline unsigned pkbf2(float a, float b) {
    __hip_bfloat162 h = __float22bfloat162_rn(make_float2(a, b));
    unsigned u;
    __builtin_memcpy(&u, &h, 4);
    return u;
}
__device__ inline float bperm_f(int addr, float v) {
    return __builtin_bit_cast(float,
        __builtin_amdgcn_ds_bpermute(addr, __builtin_bit_cast(int, v)));
}
__device__ inline float bfu_lo(unsigned u) {
    return __builtin_bit_cast(float, u << 16);
}
__device__ inline float bfu_hi(unsigned u) {
    return __builtin_bit_cast(float, u & 0xffff0000u);
}

#if __has_builtin(__builtin_amdgcn_fdot2_f32_bf16)
#define HAS_FDOT2 1
typedef __bf16 bf16x2v __attribute__((ext_vector_type(2)));
__device__ inline float fdot2bf(unsigned a, unsigned b, float c) {
    return __builtin_amdgcn_fdot2_f32_bf16(
        __builtin_bit_cast(bf16x2v, a), __builtin_bit_cast(bf16x2v, b), c, false);
}
#else
#define HAS_FDOT2 0
#endif

// ---- workspace layout (bytes) ----
#define XR8_OFS    0
#define WDEFB_OFS  16777216
#define BT27_OFS   16850944
#define BT9_OFS    16888320

#define PS_ 402   // patch plane stride (short8): c8-plane offset 1608 dw, %32=8

// ---------------- weight prep ----------------
__global__ __launch_bounds__(256) void prep_w(
    const float* __restrict__ w_off, const float* __restrict__ w_def,
    const float* __restrict__ w1, short* __restrict__ wdefB,
    short* __restrict__ bt27, short* __restrict__ bt9)
{
    int i = blockIdx.x * 256 + threadIdx.x;
    if (i < 36864) {
        int o = i / 576, r = i - o*576, t = r >> 6, c = r & 63;
        wdefB[i] = f2bf(w_def[o*576 + c*9 + t]);
    } else if (i < 36864 + 18688) {
        int j = i - 36864;
        int oc = j / 584, K = j - oc*584;
        float v = 0.f;
        if (oc < 27 && K < 576) { int t = K >> 6, c = K & 63; v = w_off[oc*576 + c*9 + t]; }
        bt27[j] = f2bf(v);
    } else if (i < 36864 + 18688 + 9344) {
        int j = i - 36864 - 18688;
        int oc = j / 584, K = j - oc*584;
        float v = 0.f;
        if (oc < 9 && K < 576) { int t = K >> 6, c = K & 63; v = w1[oc*576 + c*9 + t]; }
        bt9[j] = f2bf(v);
    }
}

// ======= fused: convert + conv27(offsets,filt) + deformable conv + residual ====
// 16x16 px tile, 256 thr (4 waves), one barrier. Both GEMMs use swapped
// operands (A=weights) so D = [oc][pixel]. Tap loop stays rolled (unroll 1 —
// larger unrolls hit compile blowup); latency overlap comes from (a) uniform
// pre-select before bpermute (halves bpermute count) and (b) prefetching tap
// t+1's offsets before tap t's blend+MFMA body.
__global__ __launch_bounds__(256, 2) void fused_off_deform(
    const float* __restrict__ x, const short8* __restrict__ btg27,
    const short8* __restrict__ wdefB, float* __restrict__ filt_out,
    short* __restrict__ xr8s)
{
    __shared__ short8 patch[8*PS_];     // [c8][py*20+px], 51,456 B
    const int tid = threadIdx.x;
    const int bx = blockIdx.x, by = blockIdx.y, n = blockIdx.z;
    const int lane = tid & 63, wid = tid >> 6;
    const int q = lane >> 4, col = lane & 15;
    const int r0 = by*16 - 2, c0 = bx*16 - 2;
    const float* xb = x + (size_t)n * C_ * HW_;

    // ---- stage 20x20 halo patch, fp32 -> bf16 (packed cvt), NC8HW8 in LDS ----
    for (int i = tid; i < 3200; i += 256) {
        int c8 = i / 400, r = i - c8*400;
        int py = r / 20, px = r - py*20;
        int gy = r0 + py, gx = c0 + px;
        uint4_ u = (uint4_){0u,0u,0u,0u};
        if ((unsigned)gy < 128u && (unsigned)gx < 128u) {
            const float* xp = xb + (size_t)(c8*8)*HW_ + gy*W_ + gx;
            u[0] = pkbf2(xp[0],      xp[HW_]);
            u[1] = pkbf2(xp[2*HW_],  xp[3*HW_]);
            u[2] = pkbf2(xp[4*HW_],  xp[5*HW_]);
            u[3] = pkbf2(xp[6*HW_],  xp[7*HW_]);
        }
        patch[c8*PS_ + py*20 + px] = __builtin_bit_cast(short8, u);
    }
    __syncthreads();

    // ---- conv27 phase (A=weights, B=patch) -> D[oc][pixel_col] ----
    float4_ a27[2][4];      // [oc-tile][row i]
    #pragma unroll
    for (int m = 0; m < 2; m++)
        #pragma unroll
        for (int i = 0; i < 4; i++) a27[m][i] = (float4_){0.f,0.f,0.f,0.f};

    #pragma unroll 2
    for (int k0 = 0; k0 < 18; k0++) {
        int t = k0 >> 1;
        int dy = t/3, dx = t - dy*3;
        int c8 = (k0 & 1)*4 + q;
        short8 w0 = btg27[col*73 + k0*4 + q];
        short8 w1 = btg27[(16 + col)*73 + k0*4 + q];
        #pragma unroll
        for (int i = 0; i < 4; i++) {
            int mt = wid*4 + i;
            short8 p = patch[c8*PS_ + (mt + dy + 1)*20 + (col + dx + 1)];
            a27[0][i] = __builtin_amdgcn_mfma_f32_16x16x32_bf16(w0, p, a27[0][i], 0,0,0);
            a27[1][i] = __builtin_amdgcn_mfma_f32_16x16x32_bf16(w1, p, a27[1][i], 0,0,0);
        }
    }

    // filt (oc 18..26) store: oc = 16 + q*4 + reg, pixel (row=wid*4+i, col)
    #pragma unroll
    for (int i = 0; i < 4; i++) {
        int prow = by*16 + wid*4 + i;
        #pragma unroll
        for (int reg = 0; reg < 4; reg++) {
            int oc = 16 + q*4 + reg;
            if (oc >= 18 && oc < 27)
                filt_out[((size_t)n*9 + (oc-18))*HW_ + prow*W_ + bx*16 + col] = a27[1][i][reg];
        }
    }

    // ---- deform phase: per wave 4 rows x 16 pixel_cols, N=64, K=576 ----
    float4_ acc[4][4];
    #pragma unroll
    for (int i = 0; i < 4; i++)
        #pragma unroll
        for (int nt = 0; nt < 4; nt++) acc[i][nt] = (float4_){0.f,0.f,0.f,0.f};

    const int col4 = col*4;
    const int gxc = bx*16 + col;

    // one tap of the deformable conv
    auto tap = [&](int t, int dy, int dx, const float* oy, const float* ox) {
        short8 afrag[4][2];
        #pragma unroll
        for (int i = 0; i < 4; i++) {
            const int gy = by*16 + wid*4 + i;
            float py = (float)(gy + dy) + oy[i];
            float px = (float)(gxc + dx) + ox[i];
            float y0f = floorf(py), x0f = floorf(px);
            float wy1 = py - y0f, wx1 = px - x0f;
            float wy0 = 1.f - wy1, wx0 = 1.f - wx1;
            int y0 = (int)y0f, x0 = (int)x0f;
            int y1 = y0 + 1,   x1 = x0 + 1;
            float wy0v = ((unsigned)y0 < (unsigned)H_) ? wy0 : 0.f;
            float wy1v = ((unsigned)y1 < (unsigned)H_) ? wy1 : 0.f;
            float wx0v = ((unsigned)x0 < (unsigned)W_) ? wx0 : 0.f;
            float wx1v = ((unsigned)x1 < (unsigned)W_) ? wx1 : 0.f;
            float w00 = wy0v*wx0v, w01 = wy0v*wx1v;
            float w10 = wy1v*wx0v, w11 = wy1v*wx1v;
            int cy0 = min(max(y0, 0), H_-1), cy1 = min(max(y1, 0), H_-1);
            int cx0 = min(max(x0, 0), W_-1), cx1 = min(max(x1, 0), W_-1);
            int ly0 = cy0 - r0, ly1 = cy1 - r0;
            int lx0 = cx0 - c0, lx1 = cx1 - c0;
            bool inp = ((unsigned)ly0 < 20u) & ((unsigned)ly1 < 20u)
                     & ((unsigned)lx0 < 20u) & ((unsigned)lx1 < 20u);
#if HAS_FDOT2
            unsigned w01pk = pkbf2(w00, w01);
            unsigned w23pk = pkbf2(w10, w11);
#endif
            #pragma unroll
            for (int ks = 0; ks < 2; ks++) {
                const int c8 = ks*4 + q;
                uint4_ u;
                if (inp) {
                    const short8* pl = &patch[c8*PS_];
                    short8 p00 = pl[ly0*20 + lx0], p01 = pl[ly0*20 + lx1];
                    short8 p10 = pl[ly1*20 + lx0], p11 = pl[ly1*20 + lx1];
#if HAS_FDOT2
                    uint4_ u00 = __builtin_bit_cast(uint4_, p00);
                    uint4_ u01 = __builtin_bit_cast(uint4_, p01);
                    uint4_ u10 = __builtin_bit_cast(uint4_, p10);
                    uint4_ u11 = __builtin_bit_cast(uint4_, p11);
                    #pragma unroll
                    for (int d = 0; d < 4; d++) {
                        unsigned lo01 = __builtin_amdgcn_perm(u01[d], u00[d], 0x05040100u);
                        unsigned hi01 = __builtin_amdgcn_perm(u01[d], u00[d], 0x07060302u);
                        unsigned lo23 = __builtin_amdgcn_perm(u11[d], u10[d], 0x05040100u);
                        unsigned hi23 = __builtin_amdgcn_perm(u11[d], u10[d], 0x07060302u);
                        float slo = fdot2bf(lo01, w01pk, fdot2bf(lo23, w23pk, 0.f));
                        float shi = fdot2bf(hi01, w01pk, fdot2bf(hi23, w23pk, 0.f));
                        u[d] = pkbf2(slo, shi);
                    }
#else
                    float s[8];
                    #pragma unroll
                    for (int j = 0; j < 8; j++)
                        s[j] = bf2f(p00[j])*w00 + bf2f(p01[j])*w01
                             + bf2f(p10[j])*w10 + bf2f(p11[j])*w11;
                    u[0] = pkbf2(s[0],s[1]); u[1] = pkbf2(s[2],s[3]);
                    u[2] = pkbf2(s[4],s[5]); u[3] = pkbf2(s[6],s[7]);
#endif
                } else {
                    // rare (|off| >= ~1): exact global fp32 fallback
                    const float* xg = xb + (size_t)(c8*8)*HW_;
                    float s[8];
                    #pragma unroll
                    for (int j = 0; j < 8; j++) {
                        const float* xj = xg + (size_t)j*HW_;
                        s[j] = xj[cy0*W_+cx0]*w00 + xj[cy0*W_+cx1]*w01
                             + xj[cy1*W_+cx0]*w10 + xj[cy1*W_+cx1]*w11;
                    }
                    u[0] = pkbf2(s[0],s[1]); u[1] = pkbf2(s[2],s[3]);
                    u[2] = pkbf2(s[4],s[5]); u[3] = pkbf2(s[6],s[7]);
                }
                afrag[i][ks] = __builtin_bit_cast(short8, u);
            }
        }
        // swapped: A=weights, B=samples -> D[oc][pixel]
        #pragma unroll
        for (int ks = 0; ks < 2; ks++) {
            #pragma unroll
            for (int nt = 0; nt < 4; nt++) {
                short8 b = wdefB[(size_t)(nt*16 + col)*72 + t*8 + ks*4 + q];
                #pragma unroll
                for (int i = 0; i < 4; i++)
                    acc[i][nt] = __builtin_amdgcn_mfma_f32_16x16x32_bf16(
                        b, afrag[i][ks], acc[i][nt], 0,0,0);
            }
        }
    };

    // ---- tap t=8 first (offsets oc 16,17 live in a27[1] regs 0,1) ----
    // Prefetch t=0's offsets before running tap 8 so their bpermute latency
    // hides under tap 8's blend+MFMA.
    float oy[4], ox[4], oyn[4], oxn[4];
    {
        float oy8[4], ox8[4];
        #pragma unroll
        for (int i = 0; i < 4; i++) {
            oy8[i] = bperm_f(col4, a27[1][i][0]);
            ox8[i] = bperm_f(col4, a27[1][i][1]);
        }
        #pragma unroll
        for (int i = 0; i < 4; i++) {        // t=0: addr=(0>>1)*64+col4, regs 0/1
            oy[i] = bperm_f(col4, a27[0][i][0]);
            ox[i] = bperm_f(col4, a27[0][i][1]);
        }
        tap(8, 1, 1, oy8, ox8);      // a27[1] dead after this point
    }
    // ---- taps 0..7, rolled; prefetch t+1's offsets before tap t's body ----
    #pragma unroll 1
    for (int t = 0; t < 8; t++) {
        if (t < 7) {
            const int t1 = t + 1;
            const int addr = ((t1 >> 1) << 6) + col4;
            #pragma unroll
            for (int i = 0; i < 4; i++) {
                // uniform pre-select (1 cndmask), then a single bpermute
                float ys = (t1 & 1) ? a27[0][i][2] : a27[0][i][0];
                float xs = (t1 & 1) ? a27[0][i][3] : a27[0][i][1];
                oyn[i] = bperm_f(addr, ys);
                oxn[i] = bperm_f(addr, xs);
            }
        }
        int dy = t/3 - 1, dx = (t - (t/3)*3) - 1;
        tap(t, dy, dx, oy, ox);
        #pragma unroll
        for (int i = 0; i < 4; i++) { oy[i] = oyn[i]; ox[i] = oxn[i]; }
    }

    // ---- epilogue: lane holds 4 consecutive channels of pixel (row i, col) ----
    const short* ps = (const short*)patch;
    short* xout = xr8s + (size_t)n*8*HW_*8;
    const int inner = (q & 1) * 4;
    #pragma unroll
    for (int i = 0; i < 4; i++) {
        const int row = wid*4 + i;
        const int pix = (by*16 + row)*W_ + bx*16 + col;
        #pragma unroll
        for (int nt = 0; nt < 4; nt++) {
            const int c8 = 2*nt + (q >> 1);
            const unsigned* pw = (const unsigned*)(ps
                + ((c8*PS_ + (row+2)*20 + (col+2)) << 3) + inner);
            unsigned r0w = pw[0], r1w = pw[1];
            float v0 = acc[i][nt][0] + bfu_lo(r0w);
            float v1 = acc[i][nt][1] + bfu_hi(r0w);
            float v2 = acc[i][nt][2] + bfu_lo(r1w);
            float v3 = acc[i][nt][3] + bfu_hi(r1w);
            uint2_ o2 = (uint2_){ pkbf2(v0, v1), pkbf2(v2, v3) };
            *(uint2_*)(xout + (((size_t)c8*HW_ + pix) << 3) + inner) = o2;
        }
    }
}

// ---------------- conv9 + BN + ReLU (B direct from global, L1-hot) -----------
__global__ __launch_bounds__(256) void conv9_mfma(
    const short8* __restrict__ xr8, const short8* __restrict__ btg,
    const float* __restrict__ gamma, const float* __restrict__ beta,
    const float* __restrict__ mean, const float* __restrict__ var,
    float* __restrict__ out)
{
    __shared__ short8 patch[8*325];
    const int tid = threadIdx.x;
    const int bx = blockIdx.x, by = blockIdx.y, n = blockIdx.z;

    for (int i = tid; i < 2592; i += 256) {
        int c8 = i / 324, r = i - c8*324;
        int py = r / 18, px = r - py*18;
        int gy = by*16 - 1 + py, gx = bx*16 - 1 + px;
        short8 v = {0,0,0,0,0,0,0,0};
        if ((unsigned)gy < 128u && (unsigned)gx < 128u)
            v = xr8[(size_t)(n*8 + c8)*HW_ + gy*W_ + gx];
        patch[c8*325 + py*18 + px] = v;
    }
    __syncthreads();

    const int lane = tid & 63, wid = tid >> 6;
    const int q = lane >> 4, col = lane & 15;
    float4_ acc[4];
    #pragma unroll
    for (int i = 0; i < 4; i++) acc[i] = (float4_){0.f,0.f,0.f,0.f};

    #pragma unroll 6
    for (int k0 = 0; k0 < 18; k0++) {
        int t = k0 >> 1;
        int dy = t/3, dx = t - dy*3;
        int c8 = (k0 & 1)*4 + q;
        short8 b0 = btg[col*73 + k0*4 + q];
        #pragma unroll
        for (int i = 0; i < 4; i++) {
            int mt = wid*4 + i;
            short8 a = patch[c8*325 + (mt + dy)*18 + (col + dx)];
            acc[i] = __builtin_amdgcn_mfma_f32_16x16x32_bf16(a, b0, acc[i], 0,0,0);
        }
    }

    float sc = 0.f, sh = 0.f;
    if (col < 9) {
        sc = gamma[col] * rsqrtf(var[col] + BN_EPS);
        sh = beta[col] - mean[col] * sc;
    }
    #pragma unroll
    for (int i = 0; i < 4; i++) {
        int mt = wid*4 + i;
        if (col < 9) {
            int pix0 = (by*16 + mt)*W_ + bx*16 + q*4;
            float4_ v;
            #pragma unroll
            for (int reg = 0; reg < 4; reg++)
                v[reg] = fmaxf(fmaf(acc[i][reg], sc, sh), 0.f);
            *(float4_*)&out[((size_t)n*9 + col)*HW_ + pix0] = v;
        }
    }
}

extern "C" void kernel_launch(void* const* d_in, const int* in_sizes, int n_in,
                              void* d_out, int out_size, void* d_ws, size_t ws_size,
                              hipStream_t stream)
{
    const float* x     = (const float*)d_in[0];
    const float* w_off = (const float*)d_in[1];
    const float* w_def = (const float*)d_in[2];
    const float* w1    = (const float*)d_in[3];
    const float* gamma = (const float*)d_in[4];
    const float* beta  = (const float*)d_in[5];
    const float* mean  = (const float*)d_in[6];
    const float* var   = (const float*)d_in[7];
    float* out = (float*)d_out;

    char* ws = (char*)d_ws;
    short8* xr8     = (short8*)(ws + XR8_OFS);
    short*  wdefB   = (short*)(ws + WDEFB_OFS);
    short*  bt27    = (short*)(ws + BT27_OFS);
    short*  bt9     = (short*)(ws + BT9_OFS);

    float* h_out    = out;
    float* filt_out = out + (size_t)N_ * 9 * HW_;

    prep_w<<<dim3(254), dim3(256), 0, stream>>>(w_off, w_def, w1, wdefB, bt27, bt9);

    dim3 cgrid(8, 8, 8);
    fused_off_deform<<<cgrid, dim3(256), 0, stream>>>(
        x, (const short8*)bt27, (const short8*)wdefB, filt_out, (short*)xr8);
    conv9_mfma<<<cgrid, dim3(256), 0, stream>>>(
        xr8, (const short8*)bt9, gamma, beta, mean, var, h_out);
}

// Round 14
// 155.094 us; speedup vs baseline: 1.0197x; 1.0176x over previous
//
#include <hip/hip_runtime.h>
#include <hip/hip_bf16.h>
#include <cmath>

#define H_ 128
#define W_ 128
#define HW_ 16384
#define C_ 64
#define N_ 8
#define BN_EPS 1e-5f

typedef __attribute__((ext_vector_type(8))) short short8;
typedef __attribute__((ext_vector_type(4))) float float4_;
typedef __attribute__((ext_vector_type(4))) unsigned uint4_;
typedef __attribute__((ext_vector_type(2))) unsigned uint2_;

__device__ inline short f2bf(float f) {
    unsigned u = __builtin_bit_cast(unsigned, f);
    u += 0x7fffu + ((u >> 16) & 1u);     // RNE
    return (short)(u >> 16);
}
__device__ inline float bf2f(short s) {
    unsigned u = ((unsigned)(unsigned short)s) << 16;
    return __builtin_bit_cast(float, u);
}
// packed RNE fp32x2 -> bf16x2 (v_cvt_pk_bf16_f32 on gfx950)
__device__ inline unsigned pkbf2(float a, float b) {
    __hip_bfloat162 h = __float22bfloat162_rn(make_float2(a, b));
    unsigned u;
    __builtin_memcpy(&u, &h, 4);
    return u;
}
__device__ inline float bperm_f(int addr, float v) {
    return __builtin_bit_cast(float,
        __builtin_amdgcn_ds_bpermute(addr, __builtin_bit_cast(int, v)));
}
__device__ inline float bfu_lo(unsigned u) {
    return __builtin_bit_cast(float, u << 16);
}
__device__ inline float bfu_hi(unsigned u) {
    return __builtin_bit_cast(float, u & 0xffff0000u);
}

#if __has_builtin(__builtin_amdgcn_fdot2_f32_bf16)
#define HAS_FDOT2 1
typedef __bf16 bf16x2v __attribute__((ext_vector_type(2)));
__device__ inline float fdot2bf(unsigned a, unsigned b, float c) {
    return __builtin_amdgcn_fdot2_f32_bf16(
        __builtin_bit_cast(bf16x2v, a), __builtin_bit_cast(bf16x2v, b), c, false);
}
#else
#define HAS_FDOT2 0
#endif

// ---- workspace layout (bytes) ----
#define XR8_OFS    0
#define WDEFB_OFS  16777216
#define BT27_OFS   16850944
#define BT9_OFS    16888320

#define PS_ 402   // patch plane stride (short8): c8-plane offset 1608 dw, %32=8

// ---------------- weight prep ----------------
__global__ __launch_bounds__(256) void prep_w(
    const float* __restrict__ w_off, const float* __restrict__ w_def,
    const float* __restrict__ w1, short* __restrict__ wdefB,
    short* __restrict__ bt27, short* __restrict__ bt9)
{
    int i = blockIdx.x * 256 + threadIdx.x;
    if (i < 36864) {
        int o = i / 576, r = i - o*576, t = r >> 6, c = r & 63;
        wdefB[i] = f2bf(w_def[o*576 + c*9 + t]);
    } else if (i < 36864 + 18688) {
        int j = i - 36864;
        int oc = j / 584, K = j - oc*584;
        float v = 0.f;
        if (oc < 27 && K < 576) { int t = K >> 6, c = K & 63; v = w_off[oc*576 + c*9 + t]; }
        bt27[j] = f2bf(v);
    } else if (i < 36864 + 18688 + 9344) {
        int j = i - 36864 - 18688;
        int oc = j / 584, K = j - oc*584;
        float v = 0.f;
        if (oc < 9 && K < 576) { int t = K >> 6, c = K & 63; v = w1[oc*576 + c*9 + t]; }
        bt9[j] = f2bf(v);
    }
}

// ======= fused: convert + conv27(offsets,filt) + deformable conv + residual ====
// 16x16 px tile, 256 thr (4 waves), one barrier. Both GEMMs use swapped
// operands (A=weights) so D = [oc][pixel]. Deform taps processed in PAIRS:
// the two tap bodies have separate local afrag registers, breaking the WAR
// hazard that serialized ds_read latency tap-by-tap in the rolled loop.
// (Full 9x unroll blows up compile time — 3 inlined tap bodies is the cap.)
__global__ __launch_bounds__(256, 2) void fused_off_deform(
    const float* __restrict__ x, const short8* __restrict__ btg27,
    const short8* __restrict__ wdefB, float* __restrict__ filt_out,
    short* __restrict__ xr8s)
{
    __shared__ short8 patch[8*PS_];     // [c8][py*20+px], 51,456 B
    const int tid = threadIdx.x;
    const int bx = blockIdx.x, by = blockIdx.y, n = blockIdx.z;
    const int lane = tid & 63, wid = tid >> 6;
    const int q = lane >> 4, col = lane & 15;
    const int r0 = by*16 - 2, c0 = bx*16 - 2;
    const float* xb = x + (size_t)n * C_ * HW_;

    // ---- stage 20x20 halo patch, fp32 -> bf16 (packed cvt), NC8HW8 in LDS ----
    for (int i = tid; i < 3200; i += 256) {
        int c8 = i / 400, r = i - c8*400;
        int py = r / 20, px = r - py*20;
        int gy = r0 + py, gx = c0 + px;
        uint4_ u = (uint4_){0u,0u,0u,0u};
        if ((unsigned)gy < 128u && (unsigned)gx < 128u) {
            const float* xp = xb + (size_t)(c8*8)*HW_ + gy*W_ + gx;
            u[0] = pkbf2(xp[0],      xp[HW_]);
            u[1] = pkbf2(xp[2*HW_],  xp[3*HW_]);
            u[2] = pkbf2(xp[4*HW_],  xp[5*HW_]);
            u[3] = pkbf2(xp[6*HW_],  xp[7*HW_]);
        }
        patch[c8*PS_ + py*20 + px] = __builtin_bit_cast(short8, u);
    }
    __syncthreads();

    // ---- conv27 phase (A=weights, B=patch) -> D[oc][pixel_col] ----
    float4_ a27[2][4];      // [oc-tile][row i]
    #pragma unroll
    for (int m = 0; m < 2; m++)
        #pragma unroll
        for (int i = 0; i < 4; i++) a27[m][i] = (float4_){0.f,0.f,0.f,0.f};

    #pragma unroll 2
    for (int k0 = 0; k0 < 18; k0++) {
        int t = k0 >> 1;
        int dy = t/3, dx = t - dy*3;
        int c8 = (k0 & 1)*4 + q;
        short8 w0 = btg27[col*73 + k0*4 + q];
        short8 w1 = btg27[(16 + col)*73 + k0*4 + q];
        #pragma unroll
        for (int i = 0; i < 4; i++) {
            int mt = wid*4 + i;
            short8 p = patch[c8*PS_ + (mt + dy + 1)*20 + (col + dx + 1)];
            a27[0][i] = __builtin_amdgcn_mfma_f32_16x16x32_bf16(w0, p, a27[0][i], 0,0,0);
            a27[1][i] = __builtin_amdgcn_mfma_f32_16x16x32_bf16(w1, p, a27[1][i], 0,0,0);
        }
    }

    // filt (oc 18..26) store: oc = 16 + q*4 + reg, pixel (row=wid*4+i, col)
    #pragma unroll
    for (int i = 0; i < 4; i++) {
        int prow = by*16 + wid*4 + i;
        #pragma unroll
        for (int reg = 0; reg < 4; reg++) {
            int oc = 16 + q*4 + reg;
            if (oc >= 18 && oc < 27)
                filt_out[((size_t)n*9 + (oc-18))*HW_ + prow*W_ + bx*16 + col] = a27[1][i][reg];
        }
    }

    // ---- deform phase: per wave 4 rows x 16 pixel_cols, N=64, K=576 ----
    float4_ acc[4][4];
    #pragma unroll
    for (int i = 0; i < 4; i++)
        #pragma unroll
        for (int nt = 0; nt < 4; nt++) acc[i][nt] = (float4_){0.f,0.f,0.f,0.f};

    const int col4 = col*4;
    const int gxc = bx*16 + col;

    // one tap of the deformable conv (afrag is LOCAL -> separate regs per call)
    auto tap = [&](int t, int dy, int dx, const float* oy, const float* ox) {
        short8 afrag[4][2];
        #pragma unroll
        for (int i = 0; i < 4; i++) {
            const int gy = by*16 + wid*4 + i;
            float py = (float)(gy + dy) + oy[i];
            float px = (float)(gxc + dx) + ox[i];
            float y0f = floorf(py), x0f = floorf(px);
            float wy1 = py - y0f, wx1 = px - x0f;
            float wy0 = 1.f - wy1, wx0 = 1.f - wx1;
            int y0 = (int)y0f, x0 = (int)x0f;
            int y1 = y0 + 1,   x1 = x0 + 1;
            float wy0v = ((unsigned)y0 < (unsigned)H_) ? wy0 : 0.f;
            float wy1v = ((unsigned)y1 < (unsigned)H_) ? wy1 : 0.f;
            float wx0v = ((unsigned)x0 < (unsigned)W_) ? wx0 : 0.f;
            float wx1v = ((unsigned)x1 < (unsigned)W_) ? wx1 : 0.f;
            float w00 = wy0v*wx0v, w01 = wy0v*wx1v;
            float w10 = wy1v*wx0v, w11 = wy1v*wx1v;
            int cy0 = min(max(y0, 0), H_-1), cy1 = min(max(y1, 0), H_-1);
            int cx0 = min(max(x0, 0), W_-1), cx1 = min(max(x1, 0), W_-1);
            int ly0 = cy0 - r0, ly1 = cy1 - r0;
            int lx0 = cx0 - c0, lx1 = cx1 - c0;
            bool inp = ((unsigned)ly0 < 20u) & ((unsigned)ly1 < 20u)
                     & ((unsigned)lx0 < 20u) & ((unsigned)lx1 < 20u);
#if HAS_FDOT2
            unsigned w01pk = pkbf2(w00, w01);
            unsigned w23pk = pkbf2(w10, w11);
#endif
            #pragma unroll
            for (int ks = 0; ks < 2; ks++) {
                const int c8 = ks*4 + q;
                uint4_ u;
                if (inp) {
                    const short8* pl = &patch[c8*PS_];
                    short8 p00 = pl[ly0*20 + lx0], p01 = pl[ly0*20 + lx1];
                    short8 p10 = pl[ly1*20 + lx0], p11 = pl[ly1*20 + lx1];
#if HAS_FDOT2
                    uint4_ u00 = __builtin_bit_cast(uint4_, p00);
                    uint4_ u01 = __builtin_bit_cast(uint4_, p01);
                    uint4_ u10 = __builtin_bit_cast(uint4_, p10);
                    uint4_ u11 = __builtin_bit_cast(uint4_, p11);
                    #pragma unroll
                    for (int d = 0; d < 4; d++) {
                        unsigned lo01 = __builtin_amdgcn_perm(u01[d], u00[d], 0x05040100u);
                        unsigned hi01 = __builtin_amdgcn_perm(u01[d], u00[d], 0x07060302u);
                        unsigned lo23 = __builtin_amdgcn_perm(u11[d], u10[d], 0x05040100u);
                        unsigned hi23 = __builtin_amdgcn_perm(u11[d], u10[d], 0x07060302u);
                        float slo = fdot2bf(lo01, w01pk, fdot2bf(lo23, w23pk, 0.f));
                        float shi = fdot2bf(hi01, w01pk, fdot2bf(hi23, w23pk, 0.f));
                        u[d] = pkbf2(slo, shi);
                    }
#else
                    float s[8];
                    #pragma unroll
                    for (int j = 0; j < 8; j++)
                        s[j] = bf2f(p00[j])*w00 + bf2f(p01[j])*w01
                             + bf2f(p10[j])*w10 + bf2f(p11[j])*w11;
                    u[0] = pkbf2(s[0],s[1]); u[1] = pkbf2(s[2],s[3]);
                    u[2] = pkbf2(s[4],s[5]); u[3] = pkbf2(s[6],s[7]);
#endif
                } else {
                    // rare (|off| >= ~1): exact global fp32 fallback
                    const float* xg = xb + (size_t)(c8*8)*HW_;
                    float s[8];
                    #pragma unroll
                    for (int j = 0; j < 8; j++) {
                        const float* xj = xg + (size_t)j*HW_;
                        s[j] = xj[cy0*W_+cx0]*w00 + xj[cy0*W_+cx1]*w01
                             + xj[cy1*W_+cx0]*w10 + xj[cy1*W_+cx1]*w11;
                    }
                    u[0] = pkbf2(s[0],s[1]); u[1] = pkbf2(s[2],s[3]);
                    u[2] = pkbf2(s[4],s[5]); u[3] = pkbf2(s[6],s[7]);
                }
                afrag[i][ks] = __builtin_bit_cast(short8, u);
            }
        }
        // swapped: A=weights, B=samples -> D[oc][pixel]
        #pragma unroll
        for (int ks = 0; ks < 2; ks++) {
            #pragma unroll
            for (int nt = 0; nt < 4; nt++) {
                short8 b = wdefB[(size_t)(nt*16 + col)*72 + t*8 + ks*4 + q];
                #pragma unroll
                for (int i = 0; i < 4; i++)
                    acc[i][nt] = __builtin_amdgcn_mfma_f32_16x16x32_bf16(
                        b, afrag[i][ks], acc[i][nt], 0,0,0);
            }
        }
    };

    // ---- tap t=8 first (offsets oc 16,17 live in a27[1] regs 0,1) ----
    {
        float oy8[4], ox8[4];
        #pragma unroll
        for (int i = 0; i < 4; i++) {
            oy8[i] = bperm_f(col4, a27[1][i][0]);
            ox8[i] = bperm_f(col4, a27[1][i][1]);
        }
        tap(8, 1, 1, oy8, ox8);      // a27[1] dead after this point
    }
    // ---- taps 0..7 in PAIRS (2tp, 2tp+1). Both taps of a pair share the
    // bpermute source lane (tp*16+col); regs {0,1} vs {2,3} are compile-time.
    // Separate afrag regs per tap body -> tap B's ds_reads overlap tap A's
    // blend + MFMA instead of stalling on the WAR hazard.
    #pragma unroll 1
    for (int tp = 0; tp < 4; tp++) {
        const int addr = (tp << 6) + col4;
        float oyA[4], oxA[4], oyB[4], oxB[4];
        #pragma unroll
        for (int i = 0; i < 4; i++) {
            oyA[i] = bperm_f(addr, a27[0][i][0]);
            oxA[i] = bperm_f(addr, a27[0][i][1]);
            oyB[i] = bperm_f(addr, a27[0][i][2]);
            oxB[i] = bperm_f(addr, a27[0][i][3]);
        }
        const int tA = 2*tp, tB = 2*tp + 1;
        tap(tA, tA/3 - 1, (tA - (tA/3)*3) - 1, oyA, oxA);
        tap(tB, tB/3 - 1, (tB - (tB/3)*3) - 1, oyB, oxB);
    }

    // ---- epilogue: lane holds 4 consecutive channels of pixel (row i, col) ----
    const short* ps = (const short*)patch;
    short* xout = xr8s + (size_t)n*8*HW_*8;
    const int inner = (q & 1) * 4;
    #pragma unroll
    for (int i = 0; i < 4; i++) {
        const int row = wid*4 + i;
        const int pix = (by*16 + row)*W_ + bx*16 + col;
        #pragma unroll
        for (int nt = 0; nt < 4; nt++) {
            const int c8 = 2*nt + (q >> 1);
            const unsigned* pw = (const unsigned*)(ps
                + ((c8*PS_ + (row+2)*20 + (col+2)) << 3) + inner);
            unsigned r0w = pw[0], r1w = pw[1];
            float v0 = acc[i][nt][0] + bfu_lo(r0w);
            float v1 = acc[i][nt][1] + bfu_hi(r0w);
            float v2 = acc[i][nt][2] + bfu_lo(r1w);
            float v3 = acc[i][nt][3] + bfu_hi(r1w);
            uint2_ o2 = (uint2_){ pkbf2(v0, v1), pkbf2(v2, v3) };
            *(uint2_*)(xout + (((size_t)c8*HW_ + pix) << 3) + inner) = o2;
        }
    }
}

// ---------------- conv9 + BN + ReLU (B direct from global, L1-hot) -----------
__global__ __launch_bounds__(256) void conv9_mfma(
    const short8* __restrict__ xr8, const short8* __restrict__ btg,
    const float* __restrict__ gamma, const float* __restrict__ beta,
    const float* __restrict__ mean, const float* __restrict__ var,
    float* __restrict__ out)
{
    __shared__ short8 patch[8*325];
    const int tid = threadIdx.x;
    const int bx = blockIdx.x, by = blockIdx.y, n = blockIdx.z;

    for (int i = tid; i < 2592; i += 256) {
        int c8 = i / 324, r = i - c8*324;
        int py = r / 18, px = r - py*18;
        int gy = by*16 - 1 + py, gx = bx*16 - 1 + px;
        short8 v = {0,0,0,0,0,0,0,0};
        if ((unsigned)gy < 128u && (unsigned)gx < 128u)
            v = xr8[(size_t)(n*8 + c8)*HW_ + gy*W_ + gx];
        patch[c8*325 + py*18 + px] = v;
    }
    __syncthreads();

    const int lane = tid & 63, wid = tid >> 6;
    const int q = lane >> 4, col = lane & 15;
    float4_ acc[4];
    #pragma unroll
    for (int i = 0; i < 4; i++) acc[i] = (float4_){0.f,0.f,0.f,0.f};

    #pragma unroll 6
    for (int k0 = 0; k0 < 18; k0++) {
        int t = k0 >> 1;
        int dy = t/3, dx = t - dy*3;
        int c8 = (k0 & 1)*4 + q;
        short8 b0 = btg[col*73 + k0*4 + q];
        #pragma unroll
        for (int i = 0; i < 4; i++) {
            int mt = wid*4 + i;
            short8 a = patch[c8*325 + (mt + dy)*18 + (col + dx)];
            acc[i] = __builtin_amdgcn_mfma_f32_16x16x32_bf16(a, b0, acc[i], 0,0,0);
        }
    }

    float sc = 0.f, sh = 0.f;
    if (col < 9) {
        sc = gamma[col] * rsqrtf(var[col] + BN_EPS);
        sh = beta[col] - mean[col] * sc;
    }
    #pragma unroll
    for (int i = 0; i < 4; i++) {
        int mt = wid*4 + i;
        if (col < 9) {
            int pix0 = (by*16 + mt)*W_ + bx*16 + q*4;
            float4_ v;
            #pragma unroll
            for (int reg = 0; reg < 4; reg++)
                v[reg] = fmaxf(fmaf(acc[i][reg], sc, sh), 0.f);
            *(float4_*)&out[((size_t)n*9 + col)*HW_ + pix0] = v;
        }
    }
}

extern "C" void kernel_launch(void* const* d_in, const int* in_sizes, int n_in,
                              void* d_out, int out_size, void* d_ws, size_t ws_size,
                              hipStream_t stream)
{
    const float* x     = (const float*)d_in[0];
    const float* w_off = (const float*)d_in[1];
    const float* w_def = (const float*)d_in[2];
    const float* w1    = (const float*)d_in[3];
    const float* gamma = (const float*)d_in[4];
    const float* beta  = (const float*)d_in[5];
    const float* mean  = (const float*)d_in[6];
    const float* var   = (const float*)d_in[7];
    float* out = (float*)d_out;

    char* ws = (char*)d_ws;
    short8* xr8     = (short8*)(ws + XR8_OFS);
    short*  wdefB   = (short*)(ws + WDEFB_OFS);
    short*  bt27    = (short*)(ws + BT27_OFS);
    short*  bt9     = (short*)(ws + BT9_OFS);

    float* h_out    = out;
    float* filt_out = out + (size_t)N_ * 9 * HW_;

    prep_w<<<dim3(254), dim3(256), 0, stream>>>(w_off, w_def, w1, wdefB, bt27, bt9);

    dim3 cgrid(8, 8, 8);
    fused_off_deform<<<cgrid, dim3(256), 0, stream>>>(
        x, (const short8*)bt27, (const short8*)wdefB, filt_out, (short*)xr8);
    conv9_mfma<<<cgrid, dim3(256), 0, stream>>>(
        xr8, (const short8*)bt9, gamma, beta, mean, var, h_out);
}